// Round 2
// baseline (1440.760 us; speedup 1.0000x reference)
//
#include <hip/hip_runtime.h>
#include <math.h>

#define B_ 4
#define S_ 2048
#define E_ 1024
#define H_ 16
#define D_ 64

typedef __attribute__((ext_vector_type(8))) short short8v;
typedef __attribute__((ext_vector_type(4))) float f32x4;

// Split fp32 x into hi (truncated bf16) + lo (bf16 of remainder).
// hi truncation error lands in lo; dropped lo*lo term ~2^-16 relative.
__device__ __forceinline__ void bf16_split(float x, short& hi, short& lo) {
    unsigned u = __float_as_uint(x);
    hi = (short)(u >> 16);
    float rest = x - __uint_as_float(u & 0xFFFF0000u);
    lo = (short)(__float_as_uint(rest) >> 16);
}

// ---------------------------------------------------------------------------
// Split-bf16 MFMA GEMM core: C(128x128 tile) = A(M=8192,K=1024) * W(K,N)
// A, W fp32 row-major. 256 threads = 4 waves, each wave 64x64 out.
// LDS image per operand: [row][slot][8] bf16 where slot = k8 ^ (row&7)
// (k8 = k>>3 within BK=64). Fragment reads are contiguous 16B, ~2-way banks.
// ---------------------------------------------------------------------------
template<int N>
__device__ __forceinline__ void gemm_core(
    const float* __restrict__ A, const float* __restrict__ W,
    int bm, int bn, int tid,
    short* Ahi, short* Alo, short* Bhi, short* Blo,
    f32x4 (&acc)[4][4])
{
    const int K = 1024;
    const int lane = tid & 63;
    const int l15 = lane & 15;
    const int l4  = lane >> 4;
    const int w   = tid >> 6;
    const int wm  = (w >> 1) * 64;
    const int wn  = (w & 1) * 64;
    const int sbase = l15 & 7;           // (row&7) for fragment reads

    // staging roles
    const int am  = tid >> 3;            // 0..31: A row within 32-row group
    const int ak8 = tid & 7;             // A k8 slot
    const int bn2 = (tid & 63) * 2;      // B col pair base 0..126
    const int bkg = tid >> 6;            // B k-group 0..3 (16 rows each)

    const float* Ab = A + (size_t)(bm * 128) * K;
    const float* Wb = W + (size_t)bn * 128;

    for (int k0 = 0; k0 < K; k0 += 64) {
        // ---- global loads into regs (issue early) ----
        float ar[4][8];
#pragma unroll
        for (int it = 0; it < 4; ++it) {
            const float* src = Ab + (size_t)(it * 32 + am) * K + k0 + ak8 * 8;
            *(float4*)&ar[it][0] = *(const float4*)src;
            *(float4*)&ar[it][4] = *(const float4*)(src + 4);
        }
        float br[16][2];
#pragma unroll
        for (int r = 0; r < 16; ++r) {
            *(float2*)&br[r][0] =
                *(const float2*)(Wb + (size_t)(k0 + bkg * 16 + r) * N + bn2);
        }

        __syncthreads();   // previous compute done reading LDS

        // ---- convert + swizzled LDS writes ----
#pragma unroll
        for (int it = 0; it < 4; ++it) {
            short8v h, l;
#pragma unroll
            for (int j = 0; j < 8; ++j) {
                short hu, lu; bf16_split(ar[it][j], hu, lu);
                h[j] = hu; l[j] = lu;
            }
            const int m = it * 32 + am;
            const int off = m * 64 + (ak8 ^ (m & 7)) * 8;
            *(short8v*)&Ahi[off] = h;
            *(short8v*)&Alo[off] = l;
        }
#pragma unroll
        for (int nn = 0; nn < 2; ++nn) {
#pragma unroll
            for (int half = 0; half < 2; ++half) {
                short8v h, l;
#pragma unroll
                for (int j = 0; j < 8; ++j) {
                    short hu, lu; bf16_split(br[half * 8 + j][nn], hu, lu);
                    h[j] = hu; l[j] = lu;
                }
                const int nab = bn2 + nn;
                const int k8  = bkg * 2 + half;
                const int off = nab * 64 + (k8 ^ (nab & 7)) * 8;
                *(short8v*)&Bhi[off] = h;
                *(short8v*)&Blo[off] = l;
            }
        }
        __syncthreads();

        // ---- MFMA: 2 k-steps of 16x16x32, 4x4 frags, 3-way split ----
#pragma unroll
        for (int kk = 0; kk < 2; ++kk) {
            const int slot = (kk * 4 + l4) ^ sbase;
            short8v ah[4], al[4];
#pragma unroll
            for (int fm = 0; fm < 4; ++fm) {
                const int off = (wm + fm * 16 + l15) * 64 + slot * 8;
                ah[fm] = *(const short8v*)&Ahi[off];
                al[fm] = *(const short8v*)&Alo[off];
            }
#pragma unroll
            for (int fn = 0; fn < 4; ++fn) {
                const int off = (wn + fn * 16 + l15) * 64 + slot * 8;
                short8v bh = *(const short8v*)&Bhi[off];
                short8v bl = *(const short8v*)&Blo[off];
#pragma unroll
                for (int fm = 0; fm < 4; ++fm) {
                    acc[fm][fn] = __builtin_amdgcn_mfma_f32_16x16x32_bf16(
                        ah[fm], bh, acc[fm][fn], 0, 0, 0);
                    acc[fm][fn] = __builtin_amdgcn_mfma_f32_16x16x32_bf16(
                        ah[fm], bl, acc[fm][fn], 0, 0, 0);
                    acc[fm][fn] = __builtin_amdgcn_mfma_f32_16x16x32_bf16(
                        al[fm], bh, acc[fm][fn], 0, 0, 0);
                }
            }
        }
    }
}

// ---------------------------------------------------------------------------
// GEMM 1: qkv = x @ W_qkv + b_qkv, scattered to q/k/v in (B,H,S,D)
// ---------------------------------------------------------------------------
__global__ __launch_bounds__(256, 2)
void gemm_qkv_kernel(const float* __restrict__ X, const float* __restrict__ W,
                     const float* __restrict__ bias,
                     float* __restrict__ q, float* __restrict__ k, float* __restrict__ v)
{
    __shared__ short Ahi[128 * 64], Alo[128 * 64], Bhi[128 * 64], Blo[128 * 64];
    const int tid = threadIdx.x;
    const int bm = blockIdx.x, bn = blockIdx.y;

    f32x4 acc[4][4];
#pragma unroll
    for (int i = 0; i < 4; ++i)
#pragma unroll
        for (int j = 0; j < 4; ++j) acc[i][j] = f32x4{0.f, 0.f, 0.f, 0.f};

    gemm_core<3 * H_ * D_>(X, W, bm, bn, tid, Ahi, Alo, Bhi, Blo, acc);

    // epilogue: bias + scatter. C row = bm*128+wm+fm*16+l4*4+r, col per lane.
    const int lane = tid & 63;
    const int l15 = lane & 15, l4 = lane >> 4;
    const int w = tid >> 6;
    const int wm = (w >> 1) * 64, wn = (w & 1) * 64;

#pragma unroll
    for (int fn = 0; fn < 4; ++fn) {
        const int c = bn * 128 + wn + fn * 16 + l15;
        const float bv = bias[c];
        const int t = c >> 10;          // 0:q 1:k 2:v
        const int h = (c >> 6) & 15;
        const int d = c & 63;
        float* dst = (t == 0) ? q : (t == 1) ? k : v;
#pragma unroll
        for (int fm = 0; fm < 4; ++fm) {
            const int rowb = bm * 128 + wm + fm * 16 + l4 * 4;
#pragma unroll
            for (int r = 0; r < 4; ++r) {
                const int row = rowb + r;
                const int b = row >> 11;         // /S_
                const int s = row & (S_ - 1);
                dst[(((size_t)b * H_ + h) * S_ + s) * D_ + d] = acc[fm][fn][r] + bv;
            }
        }
    }
}

// ---------------------------------------------------------------------------
// GEMM 2: out = ans @ W_out + b_out   (ans (B,S,H,D) = row-major 8192x1024)
// ---------------------------------------------------------------------------
__global__ __launch_bounds__(256, 2)
void gemm_out_kernel(const float* __restrict__ A, const float* __restrict__ W,
                     const float* __restrict__ bias, float* __restrict__ out)
{
    __shared__ short Ahi[128 * 64], Alo[128 * 64], Bhi[128 * 64], Blo[128 * 64];
    const int tid = threadIdx.x;
    const int bm = blockIdx.x, bn = blockIdx.y;

    f32x4 acc[4][4];
#pragma unroll
    for (int i = 0; i < 4; ++i)
#pragma unroll
        for (int j = 0; j < 4; ++j) acc[i][j] = f32x4{0.f, 0.f, 0.f, 0.f};

    gemm_core<E_>(A, W, bm, bn, tid, Ahi, Alo, Bhi, Blo, acc);

    const int lane = tid & 63;
    const int l15 = lane & 15, l4 = lane >> 4;
    const int w = tid >> 6;
    const int wm = (w >> 1) * 64, wn = (w & 1) * 64;

#pragma unroll
    for (int fn = 0; fn < 4; ++fn) {
        const int c = bn * 128 + wn + fn * 16 + l15;
        const float bv = bias[c];
#pragma unroll
        for (int fm = 0; fm < 4; ++fm) {
            const int rowb = bm * 128 + wm + fm * 16 + l4 * 4;
#pragma unroll
            for (int r = 0; r < 4; ++r)
                out[(size_t)(rowb + r) * E_ + c] = acc[fm][fn][r] + bv;
        }
    }
}

// ---------------------------------------------------------------------------
// Flash attention (causal), fp32, unchanged from baseline.
// One q row per thread; K/V tiles in LDS (uniform broadcast reads).
// ---------------------------------------------------------------------------
#define KT 32
__global__ __launch_bounds__(256, 2)
void flash_kernel(const float* __restrict__ qg, const float* __restrict__ kg,
                  const float* __restrict__ vg, float* __restrict__ ans)
{
    const int bh = blockIdx.y;
    const int b = bh >> 4;
    const int h = bh & 15;
    const float* Q = qg + (size_t)bh * S_ * D_;
    const float* K = kg + (size_t)bh * S_ * D_;
    const float* V = vg + (size_t)bh * S_ * D_;

    const int tid = threadIdx.x;
    const int qi = blockIdx.x * 256 + tid;

    float qr[D_];
#pragma unroll
    for (int d4 = 0; d4 < D_ / 4; ++d4)
        *(float4*)&qr[d4 * 4] = *(const float4*)(Q + (size_t)qi * D_ + d4 * 4);

    float o[D_];
#pragma unroll
    for (int d = 0; d < D_; ++d) o[d] = 0.f;
    float m = -1e30f, l = 0.f;

    __shared__ __align__(16) float Ks[KT][D_];
    __shared__ __align__(16) float Vs[KT][D_];

    const float scale = 0.125f;
    const int kend = blockIdx.x * 256 + 256;

    for (int k0 = 0; k0 < kend; k0 += KT) {
        __syncthreads();
        {
            const int r1 = tid >> 4, c1 = (tid & 15) << 2;
            const int r2 = r1 + 16;
            *(float4*)&Ks[r1][c1] = *(const float4*)(K + (size_t)(k0 + r1) * D_ + c1);
            *(float4*)&Vs[r1][c1] = *(const float4*)(V + (size_t)(k0 + r1) * D_ + c1);
            *(float4*)&Ks[r2][c1] = *(const float4*)(K + (size_t)(k0 + r2) * D_ + c1);
            *(float4*)&Vs[r2][c1] = *(const float4*)(V + (size_t)(k0 + r2) * D_ + c1);
        }
        __syncthreads();

        if (qi >= k0) {
            float s[KT];
            float tmax = -1e30f;
#pragma unroll
            for (int j = 0; j < KT; ++j) {
                float a0 = 0.f;
#pragma unroll
                for (int d = 0; d < D_; ++d) a0 = fmaf(qr[d], Ks[j][d], a0);
                s[j] = (k0 + j <= qi) ? a0 * scale : -1e30f;
                tmax = fmaxf(tmax, s[j]);
            }
            const float mnew = fmaxf(m, tmax);
            const float corr = __expf(m - mnew);
            l *= corr;
#pragma unroll
            for (int d = 0; d < D_; ++d) o[d] *= corr;
#pragma unroll
            for (int j = 0; j < KT; ++j) {
                const float wj = __expf(s[j] - mnew);
                l += wj;
#pragma unroll
                for (int d = 0; d < D_; ++d) o[d] = fmaf(wj, Vs[j][d], o[d]);
            }
            m = mnew;
        }
    }

    const float inv = 1.f / l;
    float* dst = ans + ((size_t)(b * S_ + qi) * H_ + h) * D_;
#pragma unroll
    for (int d4 = 0; d4 < D_ / 4; ++d4) {
        float4 t;
        t.x = o[d4 * 4 + 0] * inv;
        t.y = o[d4 * 4 + 1] * inv;
        t.z = o[d4 * 4 + 2] * inv;
        t.w = o[d4 * 4 + 3] * inv;
        *(float4*)&dst[d4 * 4] = t;
    }
}

// ---------------------------------------------------------------------------
extern "C" void kernel_launch(void* const* d_in, const int* in_sizes, int n_in,
                              void* d_out, int out_size, void* d_ws, size_t ws_size,
                              hipStream_t stream) {
    const float* x     = (const float*)d_in[0];
    const float* W_qkv = (const float*)d_in[1];
    const float* b_qkv = (const float*)d_in[2];
    const float* W_out = (const float*)d_in[3];
    const float* b_out = (const float*)d_in[4];
    float* out = (float*)d_out;

    const size_t N1 = (size_t)B_ * H_ * S_ * D_;      // 8,388,608
    const size_t need = 4 * N1 * sizeof(float);       // 128 MiB
    if (ws_size < need) return;

    float* ws  = (float*)d_ws;
    float* q   = ws;
    float* k   = ws + N1;
    float* v   = ws + 2 * N1;
    float* ans = ws + 3 * N1;                          // (B,S,H,D)

    gemm_qkv_kernel<<<dim3(64, 24), 256, 0, stream>>>(x, W_qkv, b_qkv, q, k, v);
    flash_kernel<<<dim3(S_ / 256, B_ * H_), 256, 0, stream>>>(q, k, v, ans);
    gemm_out_kernel<<<dim3(64, 8), 256, 0, stream>>>(ans, W_out, b_out, out);
}

// Round 3
// 519.436 us; speedup vs baseline: 2.7737x; 2.7737x over previous
//
#include <hip/hip_runtime.h>
#include <math.h>

#define B_ 4
#define S_ 2048
#define E_ 1024
#define H_ 16
#define D_ 64

typedef __attribute__((ext_vector_type(8))) short short8v;
typedef __attribute__((ext_vector_type(4))) float f32x4;

// Split fp32 x into hi (truncated bf16) + lo (bf16 of remainder).
__device__ __forceinline__ void bf16_split(float x, short& hi, short& lo) {
    unsigned u = __float_as_uint(x);
    hi = (short)(u >> 16);
    float rest = x - __uint_as_float(u & 0xFFFF0000u);
    lo = (short)(__float_as_uint(rest) >> 16);
}

__device__ __forceinline__ short bf16rnd(float x) {
    unsigned u = __float_as_uint(x);
    u += 0x7FFF + ((u >> 16) & 1);
    return (short)(u >> 16);
}

// ---------------------------------------------------------------------------
// Split-bf16 MFMA GEMM core (unchanged from passing round-1 kernel).
// ---------------------------------------------------------------------------
template<int N>
__device__ __forceinline__ void gemm_core(
    const float* __restrict__ A, const float* __restrict__ W,
    int bm, int bn, int tid,
    short* Ahi, short* Alo, short* Bhi, short* Blo,
    f32x4 (&acc)[4][4])
{
    const int K = 1024;
    const int lane = tid & 63;
    const int l15 = lane & 15;
    const int l4  = lane >> 4;
    const int w   = tid >> 6;
    const int wm  = (w >> 1) * 64;
    const int wn  = (w & 1) * 64;
    const int sbase = l15 & 7;

    const int am  = tid >> 3;
    const int ak8 = tid & 7;
    const int bn2 = (tid & 63) * 2;
    const int bkg = tid >> 6;

    const float* Ab = A + (size_t)(bm * 128) * K;
    const float* Wb = W + (size_t)bn * 128;

    for (int k0 = 0; k0 < K; k0 += 64) {
        float ar[4][8];
#pragma unroll
        for (int it = 0; it < 4; ++it) {
            const float* src = Ab + (size_t)(it * 32 + am) * K + k0 + ak8 * 8;
            *(float4*)&ar[it][0] = *(const float4*)src;
            *(float4*)&ar[it][4] = *(const float4*)(src + 4);
        }
        float br[16][2];
#pragma unroll
        for (int r = 0; r < 16; ++r) {
            *(float2*)&br[r][0] =
                *(const float2*)(Wb + (size_t)(k0 + bkg * 16 + r) * N + bn2);
        }

        __syncthreads();

#pragma unroll
        for (int it = 0; it < 4; ++it) {
            short8v h, l;
#pragma unroll
            for (int j = 0; j < 8; ++j) {
                short hu, lu; bf16_split(ar[it][j], hu, lu);
                h[j] = hu; l[j] = lu;
            }
            const int m = it * 32 + am;
            const int off = m * 64 + (ak8 ^ (m & 7)) * 8;
            *(short8v*)&Ahi[off] = h;
            *(short8v*)&Alo[off] = l;
        }
#pragma unroll
        for (int nn = 0; nn < 2; ++nn) {
#pragma unroll
            for (int half = 0; half < 2; ++half) {
                short8v h, l;
#pragma unroll
                for (int j = 0; j < 8; ++j) {
                    short hu, lu; bf16_split(br[half * 8 + j][nn], hu, lu);
                    h[j] = hu; l[j] = lu;
                }
                const int nab = bn2 + nn;
                const int k8  = bkg * 2 + half;
                const int off = nab * 64 + (k8 ^ (nab & 7)) * 8;
                *(short8v*)&Bhi[off] = h;
                *(short8v*)&Blo[off] = l;
            }
        }
        __syncthreads();

#pragma unroll
        for (int kk = 0; kk < 2; ++kk) {
            const int slot = (kk * 4 + l4) ^ sbase;
            short8v ah[4], al[4];
#pragma unroll
            for (int fm = 0; fm < 4; ++fm) {
                const int off = (wm + fm * 16 + l15) * 64 + slot * 8;
                ah[fm] = *(const short8v*)&Ahi[off];
                al[fm] = *(const short8v*)&Alo[off];
            }
#pragma unroll
            for (int fn = 0; fn < 4; ++fn) {
                const int off = (wn + fn * 16 + l15) * 64 + slot * 8;
                short8v bh = *(const short8v*)&Bhi[off];
                short8v bl = *(const short8v*)&Blo[off];
#pragma unroll
                for (int fm = 0; fm < 4; ++fm) {
                    acc[fm][fn] = __builtin_amdgcn_mfma_f32_16x16x32_bf16(
                        ah[fm], bh, acc[fm][fn], 0, 0, 0);
                    acc[fm][fn] = __builtin_amdgcn_mfma_f32_16x16x32_bf16(
                        ah[fm], bl, acc[fm][fn], 0, 0, 0);
                    acc[fm][fn] = __builtin_amdgcn_mfma_f32_16x16x32_bf16(
                        al[fm], bh, acc[fm][fn], 0, 0, 0);
                }
            }
        }
    }
}

// ---------------------------------------------------------------------------
// GEMM 1: qkv = x @ W_qkv + b_qkv.
// Epilogue pre-splits everything to bf16 hi/lo for the flash kernel:
//   q,k -> [b,h,s,d] (row-major over d); v -> TRANSPOSED [b,h,d,s].
// ---------------------------------------------------------------------------
__global__ __launch_bounds__(256, 2)
void gemm_qkv_kernel(const float* __restrict__ X, const float* __restrict__ W,
                     const float* __restrict__ bias,
                     short* __restrict__ q_hi, short* __restrict__ q_lo,
                     short* __restrict__ k_hi, short* __restrict__ k_lo,
                     short* __restrict__ v_hi, short* __restrict__ v_lo)
{
    __shared__ short Ahi[128 * 64], Alo[128 * 64], Bhi[128 * 64], Blo[128 * 64];
    const int tid = threadIdx.x;
    const int bm = blockIdx.x, bn = blockIdx.y;

    f32x4 acc[4][4];
#pragma unroll
    for (int i = 0; i < 4; ++i)
#pragma unroll
        for (int j = 0; j < 4; ++j) acc[i][j] = f32x4{0.f, 0.f, 0.f, 0.f};

    gemm_core<3 * H_ * D_>(X, W, bm, bn, tid, Ahi, Alo, Bhi, Blo, acc);

    const int lane = tid & 63;
    const int l15 = lane & 15, l4 = lane >> 4;
    const int w = tid >> 6;
    const int wm = (w >> 1) * 64, wn = (w & 1) * 64;

#pragma unroll
    for (int fn = 0; fn < 4; ++fn) {
        const int c = bn * 128 + wn + fn * 16 + l15;
        const float bv = bias[c];
        const int t = c >> 10;          // 0:q 1:k 2:v (uniform per block)
        const int h = (c >> 6) & 15;
        const int d = c & 63;
        if (t < 2) {
            short* dh = (t == 0) ? q_hi : k_hi;
            short* dl = (t == 0) ? q_lo : k_lo;
#pragma unroll
            for (int fm = 0; fm < 4; ++fm) {
                const int rowb = bm * 128 + wm + fm * 16 + l4 * 4;
#pragma unroll
                for (int r = 0; r < 4; ++r) {
                    const int row = rowb + r;
                    const int b = row >> 11;
                    const int s = row & (S_ - 1);
                    short hi, lo; bf16_split(acc[fm][fn][r] + bv, hi, lo);
                    const size_t off = ((size_t)(b * H_ + h) * S_ + s) * D_ + d;
                    dh[off] = hi; dl[off] = lo;
                }
            }
        } else {
#pragma unroll
            for (int fm = 0; fm < 4; ++fm) {
                const int rowb = bm * 128 + wm + fm * 16 + l4 * 4;
                const int b = rowb >> 11;
                const int s0 = rowb & (S_ - 1);
                unsigned long long ph = 0, pl = 0;
#pragma unroll
                for (int r = 0; r < 4; ++r) {
                    short hi, lo; bf16_split(acc[fm][fn][r] + bv, hi, lo);
                    ph |= ((unsigned long long)(unsigned short)hi) << (16 * r);
                    pl |= ((unsigned long long)(unsigned short)lo) << (16 * r);
                }
                const size_t base = ((size_t)(b * H_ + h) * D_ + d) * S_ + s0;
                *(unsigned long long*)&v_hi[base] = ph;
                *(unsigned long long*)&v_lo[base] = pl;
            }
        }
    }
}

// ---------------------------------------------------------------------------
// MFMA flash attention (causal). 4 waves x 16 q-rows = 64-q block, KV tile 64.
// Swapped QK^T (A=K rows, B=Q rows) -> lane holds 16 kpos scores for one q.
// PV uses the pi-permutation so P registers feed the B-operand directly;
// V staged transposed [d][slot] with the same permutation.
// ---------------------------------------------------------------------------
__global__ __launch_bounds__(256, 2)
void flash_mfma_kernel(const short* __restrict__ q_hi, const short* __restrict__ q_lo,
                       const short* __restrict__ k_hi, const short* __restrict__ k_lo,
                       const short* __restrict__ v_hi, const short* __restrict__ v_lo,
                       float* __restrict__ ans)
{
    const int bh = blockIdx.y;
    const int b = bh >> 4, h = bh & 15;
    const int qb = blockIdx.x;
    const int q0 = qb * 64;
    const int tid = threadIdx.x;
    const int lane = tid & 63;
    const int l15 = lane & 15, g = lane >> 4;
    const int w = tid >> 6;
    const int qrow = q0 + w * 16 + l15;
    const int swl = l15 & 7;

    __shared__ short Khi[64 * 64], Klo[64 * 64], Vthi[64 * 64], Vtlo[64 * 64];

    // Q fragments, held in registers the whole kernel
    short8v qh[2], ql[2];
    {
        const short* qhp = q_hi + ((size_t)bh * S_ + qrow) * D_;
        const short* qlp = q_lo + ((size_t)bh * S_ + qrow) * D_;
#pragma unroll
        for (int s = 0; s < 2; ++s) {
            qh[s] = *(const short8v*)(qhp + 32 * s + 8 * g);
            ql[s] = *(const short8v*)(qlp + 32 * s + 8 * g);
        }
    }

    f32x4 acc[4];
#pragma unroll
    for (int fd = 0; fd < 4; ++fd) acc[fd] = f32x4{0.f, 0.f, 0.f, 0.f};
    float m = -1e30f, lsum = 0.f;

    // staging roles
    const int kp = tid & 63;       // K: kpos row
    const int kw = tid >> 6;       // K: d-chunk pair
    const int vd = tid >> 2;       // V: d row
    const int vc = tid & 3;        // V: slot-chunk group
    const int vbase = 32 * (vc >> 1) + 8 * (vc & 1);

    const short* Khg = k_hi + (size_t)bh * S_ * D_;
    const short* Klg = k_lo + (size_t)bh * S_ * D_;
    const short* Vhg = v_hi + ((size_t)bh * D_ + vd) * S_;
    const short* Vlg = v_lo + ((size_t)bh * D_ + vd) * S_;

    const int nkv = qb + 1;
    for (int kb = 0; kb < nkv; ++kb) {
        const int k0 = kb * 64;

        // ---- global loads (before barrier; hide under prev compute) ----
        short8v kr_h0 = *(const short8v*)(Khg + (size_t)(k0 + kp) * D_ + 16 * kw);
        short8v kr_h1 = *(const short8v*)(Khg + (size_t)(k0 + kp) * D_ + 16 * kw + 8);
        short8v kr_l0 = *(const short8v*)(Klg + (size_t)(k0 + kp) * D_ + 16 * kw);
        short8v kr_l1 = *(const short8v*)(Klg + (size_t)(k0 + kp) * D_ + 16 * kw + 8);
        short8v v1h = *(const short8v*)(Vhg + k0 + vbase);
        short8v v2h = *(const short8v*)(Vhg + k0 + vbase + 16);
        short8v v1l = *(const short8v*)(Vlg + k0 + vbase);
        short8v v2l = *(const short8v*)(Vlg + k0 + vbase + 16);

        __syncthreads();   // previous tile fully consumed

        // K tile: [kpos][d-chunk ^ (kpos&7)]
        {
            const int o0 = kp * 64 + ((2 * kw) ^ (kp & 7)) * 8;
            const int o1 = kp * 64 + ((2 * kw + 1) ^ (kp & 7)) * 8;
            *(short8v*)&Khi[o0] = kr_h0;
            *(short8v*)&Khi[o1] = kr_h1;
            *(short8v*)&Klo[o0] = kr_l0;
            *(short8v*)&Klo[o1] = kr_l1;
        }
        // V tile transposed with pi permutation:
        // chunk 2c: {v1[0:4], v2[0:4]}, chunk 2c+1: {v1[4:8], v2[4:8]}
        {
            short8v c0h, c1h, c0l, c1l;
#pragma unroll
            for (int j = 0; j < 4; ++j) {
                c0h[j] = v1h[j];     c0h[4 + j] = v2h[j];
                c1h[j] = v1h[4 + j]; c1h[4 + j] = v2h[4 + j];
                c0l[j] = v1l[j];     c0l[4 + j] = v2l[j];
                c1l[j] = v1l[4 + j]; c1l[4 + j] = v2l[4 + j];
            }
            const int o0 = vd * 64 + ((2 * vc) ^ (vd & 7)) * 8;
            const int o1 = vd * 64 + ((2 * vc + 1) ^ (vd & 7)) * 8;
            *(short8v*)&Vthi[o0] = c0h; *(short8v*)&Vthi[o1] = c1h;
            *(short8v*)&Vtlo[o0] = c0l; *(short8v*)&Vtlo[o1] = c1l;
        }
        __syncthreads();

        // ---- QK^T: D[kpos][q], split 3-MFMA ----
        f32x4 qk[4];
#pragma unroll
        for (int f = 0; f < 4; ++f) qk[f] = f32x4{0.f, 0.f, 0.f, 0.f};
#pragma unroll
        for (int s = 0; s < 2; ++s) {
#pragma unroll
            for (int f = 0; f < 4; ++f) {
                const int off = (16 * f + l15) * 64 + ((4 * s + g) ^ swl) * 8;
                short8v kh = *(const short8v*)&Khi[off];
                short8v kl = *(const short8v*)&Klo[off];
                qk[f] = __builtin_amdgcn_mfma_f32_16x16x32_bf16(kh, qh[s], qk[f], 0, 0, 0);
                qk[f] = __builtin_amdgcn_mfma_f32_16x16x32_bf16(kh, ql[s], qk[f], 0, 0, 0);
                qk[f] = __builtin_amdgcn_mfma_f32_16x16x32_bf16(kl, qh[s], qk[f], 0, 0, 0);
            }
        }

        // ---- online softmax (lane-local + 2 shfl) ----
        float p[4][4];
        float tmax = -1e30f;
#pragma unroll
        for (int f = 0; f < 4; ++f)
#pragma unroll
            for (int r = 0; r < 4; ++r) {
                const int kpos = k0 + 16 * f + 4 * g + r;
                float sv = qk[f][r] * 0.125f;
                sv = (kpos <= qrow) ? sv : -1e30f;
                p[f][r] = sv;
                tmax = fmaxf(tmax, sv);
            }
        tmax = fmaxf(tmax, __shfl_xor(tmax, 16));
        tmax = fmaxf(tmax, __shfl_xor(tmax, 32));
        const float mnew = fmaxf(m, tmax);
        const float corr = __expf(m - mnew);
#pragma unroll
        for (int fd = 0; fd < 4; ++fd) acc[fd] *= corr;
        float ls = 0.f;
#pragma unroll
        for (int f = 0; f < 4; ++f)
#pragma unroll
            for (int r = 0; r < 4; ++r) {
                const float e = __expf(p[f][r] - mnew);
                p[f][r] = e;
                ls += e;
            }
        ls += __shfl_xor(ls, 16);
        ls += __shfl_xor(ls, 32);
        lsum = lsum * corr + ls;
        m = mnew;

        // ---- pack P into B-operands (pi makes this lane-local) ----
        short8v pb0, pb1;
#pragma unroll
        for (int j = 0; j < 4; ++j) {
            pb0[j]     = bf16rnd(p[0][j]);
            pb0[4 + j] = bf16rnd(p[1][j]);
            pb1[j]     = bf16rnd(p[2][j]);
            pb1[4 + j] = bf16rnd(p[3][j]);
        }

        // ---- PV: acc[d][q] += Vt * P ----
#pragma unroll
        for (int t = 0; t < 2; ++t) {
            const short8v pb = t ? pb1 : pb0;
#pragma unroll
            for (int fd = 0; fd < 4; ++fd) {
                const int off = (16 * fd + l15) * 64 + ((4 * t + g) ^ swl) * 8;
                short8v vh = *(const short8v*)&Vthi[off];
                short8v vl = *(const short8v*)&Vtlo[off];
                acc[fd] = __builtin_amdgcn_mfma_f32_16x16x32_bf16(vh, pb, acc[fd], 0, 0, 0);
                acc[fd] = __builtin_amdgcn_mfma_f32_16x16x32_bf16(vl, pb, acc[fd], 0, 0, 0);
            }
        }
    }

    // ---- normalize + write: ans[b, s=qrow, h, d], d = 16*fd + 4*g + r ----
    const float inv = 1.f / lsum;
    float* dst = ans + ((size_t)(b * S_ + qrow)) * (H_ * D_) + h * D_;
#pragma unroll
    for (int fd = 0; fd < 4; ++fd) {
        f32x4 o = acc[fd] * inv;
        *(f32x4*)&dst[16 * fd + 4 * g] = o;
    }
}

// ---------------------------------------------------------------------------
// GEMM 2: out = ans @ W_out + b_out (unchanged)
// ---------------------------------------------------------------------------
__global__ __launch_bounds__(256, 2)
void gemm_out_kernel(const float* __restrict__ A, const float* __restrict__ W,
                     const float* __restrict__ bias, float* __restrict__ out)
{
    __shared__ short Ahi[128 * 64], Alo[128 * 64], Bhi[128 * 64], Blo[128 * 64];
    const int tid = threadIdx.x;
    const int bm = blockIdx.x, bn = blockIdx.y;

    f32x4 acc[4][4];
#pragma unroll
    for (int i = 0; i < 4; ++i)
#pragma unroll
        for (int j = 0; j < 4; ++j) acc[i][j] = f32x4{0.f, 0.f, 0.f, 0.f};

    gemm_core<E_>(A, W, bm, bn, tid, Ahi, Alo, Bhi, Blo, acc);

    const int lane = tid & 63;
    const int l15 = lane & 15, l4 = lane >> 4;
    const int w = tid >> 6;
    const int wm = (w >> 1) * 64, wn = (w & 1) * 64;

#pragma unroll
    for (int fn = 0; fn < 4; ++fn) {
        const int c = bn * 128 + wn + fn * 16 + l15;
        const float bv = bias[c];
#pragma unroll
        for (int fm = 0; fm < 4; ++fm) {
            const int rowb = bm * 128 + wm + fm * 16 + l4 * 4;
#pragma unroll
            for (int r = 0; r < 4; ++r)
                out[(size_t)(rowb + r) * E_ + c] = acc[fm][fn][r] + bv;
        }
    }
}

// ---------------------------------------------------------------------------
extern "C" void kernel_launch(void* const* d_in, const int* in_sizes, int n_in,
                              void* d_out, int out_size, void* d_ws, size_t ws_size,
                              hipStream_t stream) {
    const float* x     = (const float*)d_in[0];
    const float* W_qkv = (const float*)d_in[1];
    const float* b_qkv = (const float*)d_in[2];
    const float* W_out = (const float*)d_in[3];
    const float* b_out = (const float*)d_in[4];
    float* out = (float*)d_out;

    const size_t N1 = (size_t)B_ * H_ * S_ * D_;      // 8,388,608
    const size_t need = 4 * N1 * sizeof(float);       // 128 MiB
    if (ws_size < need) return;

    short* q_hi = (short*)d_ws;
    short* q_lo = q_hi + N1;
    short* k_hi = q_lo + N1;
    short* k_lo = k_hi + N1;
    short* v_hi = k_lo + N1;          // [b,h,d,s]
    short* v_lo = v_hi + N1;
    float* ans  = (float*)(v_lo + N1); // [b,s,h,d] fp32, 32 MiB

    gemm_qkv_kernel<<<dim3(64, 24), 256, 0, stream>>>(
        x, W_qkv, b_qkv, q_hi, q_lo, k_hi, k_lo, v_hi, v_lo);
    flash_mfma_kernel<<<dim3(S_ / 64, B_ * H_), 256, 0, stream>>>(
        q_hi, q_lo, k_hi, k_lo, v_hi, v_lo, ans);
    gemm_out_kernel<<<dim3(64, 8), 256, 0, stream>>>(ans, W_out, b_out, out);
}

// Round 5
// 304.179 us; speedup vs baseline: 4.7366x; 1.7077x over previous
//
#include <hip/hip_runtime.h>
#include <math.h>

#define B_ 4
#define S_ 2048
#define E_ 1024
#define H_ 16
#define D_ 64

typedef _Float16 half8v __attribute__((ext_vector_type(8)));
typedef _Float16 half4v __attribute__((ext_vector_type(4)));
typedef __attribute__((ext_vector_type(4))) float f32x4;

// ---------------------------------------------------------------------------
// Pre-convert kernels: fp32 -> fp16 (straight), fp32 -> fp16 transposed.
// ---------------------------------------------------------------------------
__global__ __launch_bounds__(256)
void convert_f32_f16_kernel(const float* __restrict__ in, _Float16* __restrict__ out, int n4)
{
    const int i = blockIdx.x * 256 + threadIdx.x;
    if (i < n4) {
        float4 v = ((const float4*)in)[i];
        half4v h;
        h[0] = (_Float16)v.x; h[1] = (_Float16)v.y;
        h[2] = (_Float16)v.z; h[3] = (_Float16)v.w;
        ((half4v*)out)[i] = h;
    }
}

// in: R x C fp32 row-major; out: C x R fp16 (out[c][r] = in[r][c])
__global__ __launch_bounds__(256, 4)
void transpose_f32_f16_kernel(const float* __restrict__ in, _Float16* __restrict__ out,
                              int R, int C)
{
    __shared__ float tile[64][65];
    const int r0 = blockIdx.x * 64, c0 = blockIdx.y * 64;
    const int tr = threadIdx.x >> 6, tc = threadIdx.x & 63;
#pragma unroll
    for (int i = 0; i < 16; ++i)
        tile[i * 4 + tr][tc] = in[(size_t)(r0 + i * 4 + tr) * C + c0 + tc];
    __syncthreads();
#pragma unroll
    for (int i = 0; i < 16; ++i)
        out[(size_t)(c0 + i * 4 + tr) * R + r0 + tc] = (_Float16)tile[tc][i * 4 + tr];
}

// ---------------------------------------------------------------------------
// fp16 MFMA GEMM core. A: M x K fp16 (k-contiguous). Bt: N x K fp16
// (k-contiguous, i.e. W transposed). 128x128 tile, BK=64, 4 waves x 64x64.
// LDS image [row][slot^(row&7)][8] halves; reg-prefetch of next K-step.
// ---------------------------------------------------------------------------
__device__ __forceinline__ void gemm_core_f16(
    const _Float16* __restrict__ A, const _Float16* __restrict__ Bt,
    int bm, int bn, int tid,
    _Float16* As, _Float16* Bs,
    f32x4 (&acc)[4][4])
{
    const int K = 1024;
    const int lane = tid & 63;
    const int l15 = lane & 15, g = lane >> 4;
    const int w = tid >> 6;
    const int wm = (w >> 1) * 64, wn = (w & 1) * 64;
    const int swl = l15 & 7;

    const int sr = tid >> 3;   // staging row within 32-row group
    const int sk = tid & 7;    // staging k8 slot

    const _Float16* Ab = A + (size_t)(bm * 128) * K;
    const _Float16* Bb = Bt + (size_t)(bn * 128) * K;

    half8v arg[4], brg[4];
#pragma unroll
    for (int it = 0; it < 4; ++it) {
        arg[it] = *(const half8v*)(Ab + (size_t)(it * 32 + sr) * K + sk * 8);
        brg[it] = *(const half8v*)(Bb + (size_t)(it * 32 + sr) * K + sk * 8);
    }

    for (int k0 = 0; k0 < K; k0 += 64) {
        __syncthreads();   // previous compute done reading LDS
#pragma unroll
        for (int it = 0; it < 4; ++it) {
            const int r = it * 32 + sr;
            const int off = r * 64 + (sk ^ (r & 7)) * 8;
            *(half8v*)&As[off] = arg[it];
            *(half8v*)&Bs[off] = brg[it];
        }
        __syncthreads();
        if (k0 + 64 < K) {   // prefetch next K-step; overlaps MFMAs below
#pragma unroll
            for (int it = 0; it < 4; ++it) {
                arg[it] = *(const half8v*)(Ab + (size_t)(it * 32 + sr) * K + k0 + 64 + sk * 8);
                brg[it] = *(const half8v*)(Bb + (size_t)(it * 32 + sr) * K + k0 + 64 + sk * 8);
            }
        }
#pragma unroll
        for (int kk = 0; kk < 2; ++kk) {
            const int slot = (kk * 4 + g) ^ swl;
            half8v af[4];
#pragma unroll
            for (int fm = 0; fm < 4; ++fm)
                af[fm] = *(const half8v*)&As[(wm + fm * 16 + l15) * 64 + slot * 8];
#pragma unroll
            for (int fn = 0; fn < 4; ++fn) {
                half8v bf = *(const half8v*)&Bs[(wn + fn * 16 + l15) * 64 + slot * 8];
#pragma unroll
                for (int fm = 0; fm < 4; ++fm)
                    acc[fm][fn] = __builtin_amdgcn_mfma_f32_16x16x32_f16(
                        af[fm], bf, acc[fm][fn], 0, 0, 0);
            }
        }
    }
}

// ---------------------------------------------------------------------------
// GEMM 1: qkv = x @ W_qkv + b_qkv. q,k -> fp16 [b,h,s,d]; v -> fp16 [b,h,d,s].
// ---------------------------------------------------------------------------
__global__ __launch_bounds__(256, 2)
void gemm_qkv_f16_kernel(const _Float16* __restrict__ Xh, const _Float16* __restrict__ Wqh,
                         const float* __restrict__ bias,
                         _Float16* __restrict__ qf, _Float16* __restrict__ kf,
                         _Float16* __restrict__ vf)
{
    __shared__ _Float16 As[128 * 64], Bs[128 * 64];
    const int tid = threadIdx.x;
    const int bm = blockIdx.x, bn = blockIdx.y;

    f32x4 acc[4][4];
#pragma unroll
    for (int i = 0; i < 4; ++i)
#pragma unroll
        for (int j = 0; j < 4; ++j) acc[i][j] = f32x4{0.f, 0.f, 0.f, 0.f};

    gemm_core_f16(Xh, Wqh, bm, bn, tid, As, Bs, acc);

    const int lane = tid & 63;
    const int l15 = lane & 15, l4 = lane >> 4;
    const int w = tid >> 6;
    const int wm = (w >> 1) * 64, wn = (w & 1) * 64;

#pragma unroll
    for (int fn = 0; fn < 4; ++fn) {
        const int c = bn * 128 + wn + fn * 16 + l15;
        const float bv = bias[c];
        const int t = c >> 10;          // 0:q 1:k 2:v (uniform per block)
        const int h = (c >> 6) & 15;
        const int d = c & 63;
        if (t < 2) {
            _Float16* dst = (t == 0) ? qf : kf;
#pragma unroll
            for (int fm = 0; fm < 4; ++fm) {
                const int rowb = bm * 128 + wm + fm * 16 + l4 * 4;
#pragma unroll
                for (int r = 0; r < 4; ++r) {
                    const int row = rowb + r;
                    const int b = row >> 11;
                    const int s = row & (S_ - 1);
                    dst[((size_t)(b * H_ + h) * S_ + s) * D_ + d] =
                        (_Float16)(acc[fm][fn][r] + bv);
                }
            }
        } else {
#pragma unroll
            for (int fm = 0; fm < 4; ++fm) {
                const int rowb = bm * 128 + wm + fm * 16 + l4 * 4;
                const int b = rowb >> 11;
                const int s0 = rowb & (S_ - 1);
                half4v pk;
#pragma unroll
                for (int r = 0; r < 4; ++r) pk[r] = (_Float16)(acc[fm][fn][r] + bv);
                *(half4v*)&vf[((size_t)(b * H_ + h) * D_ + d) * S_ + s0] = pk;
            }
        }
    }
}

// ---------------------------------------------------------------------------
// fp16 MFMA flash attention (causal). Round-3-validated structure; now
// single-MFMA fp16, reg-prefetch of next K/V tile, heavy-first qb order.
// __launch_bounds__(256,4): 16 KB LDS + ~100 VGPR -> 4 blocks/CU resident.
// ---------------------------------------------------------------------------
__global__ __launch_bounds__(256, 4)
void flash_f16_kernel(const _Float16* __restrict__ qf, const _Float16* __restrict__ kf,
                      const _Float16* __restrict__ vf, _Float16* __restrict__ ansh)
{
    const int bh = blockIdx.y;
    const int b = bh >> 4, h = bh & 15;
    const int qb = (S_ / 64 - 1) - blockIdx.x;   // heaviest blocks dispatch first
    const int q0 = qb * 64;
    const int tid = threadIdx.x;
    const int lane = tid & 63;
    const int l15 = lane & 15, g = lane >> 4;
    const int w = tid >> 6;
    const int qrow = q0 + w * 16 + l15;
    const int swl = l15 & 7;

    __shared__ _Float16 Kh[64 * 64];
    __shared__ _Float16 Vth[64 * 64];

    half8v qh[2];
    {
        const _Float16* qp = qf + ((size_t)bh * S_ + qrow) * D_;
#pragma unroll
        for (int s = 0; s < 2; ++s) qh[s] = *(const half8v*)(qp + 32 * s + 8 * g);
    }

    f32x4 acc[4];
#pragma unroll
    for (int fd = 0; fd < 4; ++fd) acc[fd] = f32x4{0.f, 0.f, 0.f, 0.f};
    float m = -1e30f, lsum = 0.f;

    const int kp = tid & 63;       // K: kpos row
    const int kw = tid >> 6;       // K: d-chunk pair
    const int vd = tid >> 2;       // V: d row
    const int vc = tid & 3;        // V: slot-chunk group
    const int vbase = 32 * (vc >> 1) + 8 * (vc & 1);

    const _Float16* Kg = kf + (size_t)bh * S_ * D_;
    const _Float16* Vg = vf + ((size_t)bh * D_ + vd) * S_;

    const int nkv = qb + 1;

    half8v krA = *(const half8v*)(Kg + (size_t)kp * D_ + 16 * kw);
    half8v krB = *(const half8v*)(Kg + (size_t)kp * D_ + 16 * kw + 8);
    half8v vrA = *(const half8v*)(Vg + vbase);
    half8v vrB = *(const half8v*)(Vg + vbase + 16);

    for (int kb = 0; kb < nkv; ++kb) {
        const int k0 = kb * 64;
        __syncthreads();
        {
            const int o0 = kp * 64 + ((2 * kw) ^ (kp & 7)) * 8;
            const int o1 = kp * 64 + ((2 * kw + 1) ^ (kp & 7)) * 8;
            *(half8v*)&Kh[o0] = krA;
            *(half8v*)&Kh[o1] = krB;
            half8v c0, c1;
#pragma unroll
            for (int j = 0; j < 4; ++j) {
                c0[j] = vrA[j];     c0[4 + j] = vrB[j];
                c1[j] = vrA[4 + j]; c1[4 + j] = vrB[4 + j];
            }
            const int p0 = vd * 64 + ((2 * vc) ^ (vd & 7)) * 8;
            const int p1 = vd * 64 + ((2 * vc + 1) ^ (vd & 7)) * 8;
            *(half8v*)&Vth[p0] = c0;
            *(half8v*)&Vth[p1] = c1;
        }
        __syncthreads();
        if (kb + 1 < nkv) {
            const int kn = k0 + 64;
            krA = *(const half8v*)(Kg + (size_t)(kn + kp) * D_ + 16 * kw);
            krB = *(const half8v*)(Kg + (size_t)(kn + kp) * D_ + 16 * kw + 8);
            vrA = *(const half8v*)(Vg + kn + vbase);
            vrB = *(const half8v*)(Vg + kn + vbase + 16);
        }

        f32x4 qk[4];
#pragma unroll
        for (int f = 0; f < 4; ++f) qk[f] = f32x4{0.f, 0.f, 0.f, 0.f};
#pragma unroll
        for (int s = 0; s < 2; ++s) {
#pragma unroll
            for (int f = 0; f < 4; ++f) {
                const int off = (16 * f + l15) * 64 + ((4 * s + g) ^ swl) * 8;
                half8v kv = *(const half8v*)&Kh[off];
                qk[f] = __builtin_amdgcn_mfma_f32_16x16x32_f16(kv, qh[s], qk[f], 0, 0, 0);
            }
        }

        float p[4][4];
        float tmax = -1e30f;
#pragma unroll
        for (int f = 0; f < 4; ++f)
#pragma unroll
            for (int r = 0; r < 4; ++r) {
                const int kpos = k0 + 16 * f + 4 * g + r;
                float sv = qk[f][r] * 0.125f;
                sv = (kpos <= qrow) ? sv : -1e30f;
                p[f][r] = sv;
                tmax = fmaxf(tmax, sv);
            }
        tmax = fmaxf(tmax, __shfl_xor(tmax, 16));
        tmax = fmaxf(tmax, __shfl_xor(tmax, 32));
        const float mnew = fmaxf(m, tmax);
        const float corr = __expf(m - mnew);
#pragma unroll
        for (int fd = 0; fd < 4; ++fd) acc[fd] *= corr;
        float ls = 0.f;
#pragma unroll
        for (int f = 0; f < 4; ++f)
#pragma unroll
            for (int r = 0; r < 4; ++r) {
                const float e = __expf(p[f][r] - mnew);
                p[f][r] = e;
                ls += e;
            }
        ls += __shfl_xor(ls, 16);
        ls += __shfl_xor(ls, 32);
        lsum = lsum * corr + ls;
        m = mnew;

        half8v pb0, pb1;
#pragma unroll
        for (int j = 0; j < 4; ++j) {
            pb0[j]     = (_Float16)p[0][j];
            pb0[4 + j] = (_Float16)p[1][j];
            pb1[j]     = (_Float16)p[2][j];
            pb1[4 + j] = (_Float16)p[3][j];
        }

#pragma unroll
        for (int t = 0; t < 2; ++t) {
            const half8v pb = t ? pb1 : pb0;
#pragma unroll
            for (int fd = 0; fd < 4; ++fd) {
                const int off = (16 * fd + l15) * 64 + ((4 * t + g) ^ swl) * 8;
                half8v vv = *(const half8v*)&Vth[off];
                acc[fd] = __builtin_amdgcn_mfma_f32_16x16x32_f16(vv, pb, acc[fd], 0, 0, 0);
            }
        }
    }

    const float inv = 1.f / lsum;
    _Float16* dst = ansh + ((size_t)(b * S_ + qrow) * H_ + h) * D_;
#pragma unroll
    for (int fd = 0; fd < 4; ++fd) {
        half4v o4;
#pragma unroll
        for (int r = 0; r < 4; ++r) o4[r] = (_Float16)(acc[fd][r] * inv);
        *(half4v*)&dst[16 * fd + 4 * g] = o4;
    }
}

// ---------------------------------------------------------------------------
// GEMM 2: out = ans @ W_out + b_out. A = ans fp16, Bt = W_out^T fp16.
// ---------------------------------------------------------------------------
__global__ __launch_bounds__(256, 2)
void gemm_out_f16_kernel(const _Float16* __restrict__ Ah, const _Float16* __restrict__ Woh,
                         const float* __restrict__ bias, float* __restrict__ out)
{
    __shared__ _Float16 As[128 * 64], Bs[128 * 64];
    const int tid = threadIdx.x;
    const int bm = blockIdx.x, bn = blockIdx.y;

    f32x4 acc[4][4];
#pragma unroll
    for (int i = 0; i < 4; ++i)
#pragma unroll
        for (int j = 0; j < 4; ++j) acc[i][j] = f32x4{0.f, 0.f, 0.f, 0.f};

    gemm_core_f16(Ah, Woh, bm, bn, tid, As, Bs, acc);

    const int lane = tid & 63;
    const int l15 = lane & 15, l4 = lane >> 4;
    const int w = tid >> 6;
    const int wm = (w >> 1) * 64, wn = (w & 1) * 64;

#pragma unroll
    for (int fn = 0; fn < 4; ++fn) {
        const int c = bn * 128 + wn + fn * 16 + l15;
        const float bv = bias[c];
#pragma unroll
        for (int fm = 0; fm < 4; ++fm) {
            const int rowb = bm * 128 + wm + fm * 16 + l4 * 4;
#pragma unroll
            for (int r = 0; r < 4; ++r)
                out[(size_t)(rowb + r) * E_ + c] = acc[fm][fn][r] + bv;
        }
    }
}

// ---------------------------------------------------------------------------
extern "C" void kernel_launch(void* const* d_in, const int* in_sizes, int n_in,
                              void* d_out, int out_size, void* d_ws, size_t ws_size,
                              hipStream_t stream) {
    const float* x     = (const float*)d_in[0];
    const float* W_qkv = (const float*)d_in[1];
    const float* b_qkv = (const float*)d_in[2];
    const float* W_out = (const float*)d_in[3];
    const float* b_out = (const float*)d_in[4];
    float* out = (float*)d_out;

    const size_t N1 = (size_t)B_ * H_ * S_ * D_;       // 8,388,608
    const size_t MK = (size_t)8192 * 1024;
    const size_t WQ = (size_t)3072 * 1024;
    const size_t WO = (size_t)1024 * 1024;
    const size_t need = (MK + WQ + WO + 4 * N1) * sizeof(_Float16);  // ~92 MiB
    if (ws_size < need) return;

    _Float16* Xh   = (_Float16*)d_ws;
    _Float16* Wqh  = Xh + MK;        // W_qkv^T: [3072][1024]
    _Float16* Woh  = Wqh + WQ;       // W_out^T: [1024][1024]
    _Float16* qf   = Woh + WO;       // [b,h,s,d]
    _Float16* kf   = qf + N1;        // [b,h,s,d]
    _Float16* vf   = kf + N1;        // [b,h,d,s]
    _Float16* ansh = vf + N1;        // [b,s,h,d]

    convert_f32_f16_kernel<<<(int)(MK / 4 / 256), 256, 0, stream>>>(x, Xh, (int)(MK / 4));
    transpose_f32_f16_kernel<<<dim3(16, 48), 256, 0, stream>>>(W_qkv, Wqh, 1024, 3072);
    transpose_f32_f16_kernel<<<dim3(16, 16), 256, 0, stream>>>(W_out, Woh, 1024, 1024);

    gemm_qkv_f16_kernel<<<dim3(64, 24), 256, 0, stream>>>(Xh, Wqh, b_qkv, qf, kf, vf);
    flash_f16_kernel<<<dim3(S_ / 64, B_ * H_), 256, 0, stream>>>(qf, kf, vf, ansh);
    gemm_out_f16_kernel<<<dim3(64, 8), 256, 0, stream>>>(ansh, Woh, b_out, out);
}

// Round 6
// 287.638 us; speedup vs baseline: 5.0089x; 1.0575x over previous
//
#include <hip/hip_runtime.h>
#include <math.h>

#define B_ 4
#define S_ 2048
#define E_ 1024
#define H_ 16
#define D_ 64

typedef _Float16 half8v __attribute__((ext_vector_type(8)));
typedef _Float16 half4v __attribute__((ext_vector_type(4)));
typedef __attribute__((ext_vector_type(4))) float f32x4;

// ---------------------------------------------------------------------------
// Pre-convert kernels: fp32 -> fp16 (straight), fp32 -> fp16 transposed.
// ---------------------------------------------------------------------------
__global__ __launch_bounds__(256)
void convert_f32_f16_kernel(const float* __restrict__ in, _Float16* __restrict__ out, int n4)
{
    const int i = blockIdx.x * 256 + threadIdx.x;
    if (i < n4) {
        float4 v = ((const float4*)in)[i];
        half4v h;
        h[0] = (_Float16)v.x; h[1] = (_Float16)v.y;
        h[2] = (_Float16)v.z; h[3] = (_Float16)v.w;
        ((half4v*)out)[i] = h;
    }
}

// in: R x C fp32 row-major; out: C x R fp16 (out[c][r] = in[r][c])
__global__ __launch_bounds__(256, 4)
void transpose_f32_f16_kernel(const float* __restrict__ in, _Float16* __restrict__ out,
                              int R, int C)
{
    __shared__ float tile[64][65];
    const int r0 = blockIdx.x * 64, c0 = blockIdx.y * 64;
    const int tr = threadIdx.x >> 6, tc = threadIdx.x & 63;
#pragma unroll
    for (int i = 0; i < 16; ++i)
        tile[i * 4 + tr][tc] = in[(size_t)(r0 + i * 4 + tr) * C + c0 + tc];
    __syncthreads();
#pragma unroll
    for (int i = 0; i < 16; ++i)
        out[(size_t)(c0 + i * 4 + tr) * R + r0 + tc] = (_Float16)tile[tc][i * 4 + tr];
}

// ---------------------------------------------------------------------------
// fp16 MFMA GEMM core (validated round 5). A: M x K fp16, Bt: N x K fp16.
// 128x128 tile, BK=64, 4 waves x 64x64. Swizzled LDS, reg-prefetch.
// ---------------------------------------------------------------------------
__device__ __forceinline__ void gemm_core_f16(
    const _Float16* __restrict__ A, const _Float16* __restrict__ Bt,
    int bm, int bn, int tid,
    _Float16* As, _Float16* Bs,
    f32x4 (&acc)[4][4])
{
    const int K = 1024;
    const int lane = tid & 63;
    const int l15 = lane & 15, g = lane >> 4;
    const int w = tid >> 6;
    const int wm = (w >> 1) * 64, wn = (w & 1) * 64;
    const int swl = l15 & 7;

    const int sr = tid >> 3;
    const int sk = tid & 7;

    const _Float16* Ab = A + (size_t)(bm * 128) * K;
    const _Float16* Bb = Bt + (size_t)(bn * 128) * K;

    half8v arg[4], brg[4];
#pragma unroll
    for (int it = 0; it < 4; ++it) {
        arg[it] = *(const half8v*)(Ab + (size_t)(it * 32 + sr) * K + sk * 8);
        brg[it] = *(const half8v*)(Bb + (size_t)(it * 32 + sr) * K + sk * 8);
    }

    for (int k0 = 0; k0 < K; k0 += 64) {
        __syncthreads();
#pragma unroll
        for (int it = 0; it < 4; ++it) {
            const int r = it * 32 + sr;
            const int off = r * 64 + (sk ^ (r & 7)) * 8;
            *(half8v*)&As[off] = arg[it];
            *(half8v*)&Bs[off] = brg[it];
        }
        __syncthreads();
        if (k0 + 64 < K) {
#pragma unroll
            for (int it = 0; it < 4; ++it) {
                arg[it] = *(const half8v*)(Ab + (size_t)(it * 32 + sr) * K + k0 + 64 + sk * 8);
                brg[it] = *(const half8v*)(Bb + (size_t)(it * 32 + sr) * K + k0 + 64 + sk * 8);
            }
        }
#pragma unroll
        for (int kk = 0; kk < 2; ++kk) {
            const int slot = (kk * 4 + g) ^ swl;
            half8v af[4];
#pragma unroll
            for (int fm = 0; fm < 4; ++fm)
                af[fm] = *(const half8v*)&As[(wm + fm * 16 + l15) * 64 + slot * 8];
#pragma unroll
            for (int fn = 0; fn < 4; ++fn) {
                half8v bf = *(const half8v*)&Bs[(wn + fn * 16 + l15) * 64 + slot * 8];
#pragma unroll
                for (int fm = 0; fm < 4; ++fm)
                    acc[fm][fn] = __builtin_amdgcn_mfma_f32_16x16x32_f16(
                        af[fm], bf, acc[fm][fn], 0, 0, 0);
            }
        }
    }
}

// ---------------------------------------------------------------------------
// GEMM 1: qkv = x @ W_qkv + b_qkv. q,k -> fp16 [b,h,s,d]; v -> fp16 [b,h,d,s].
// ---------------------------------------------------------------------------
__global__ __launch_bounds__(256, 2)
void gemm_qkv_f16_kernel(const _Float16* __restrict__ Xh, const _Float16* __restrict__ Wqh,
                         const float* __restrict__ bias,
                         _Float16* __restrict__ qf, _Float16* __restrict__ kf,
                         _Float16* __restrict__ vf)
{
    __shared__ _Float16 As[128 * 64], Bs[128 * 64];
    const int tid = threadIdx.x;
    const int bm = blockIdx.x, bn = blockIdx.y;

    f32x4 acc[4][4];
#pragma unroll
    for (int i = 0; i < 4; ++i)
#pragma unroll
        for (int j = 0; j < 4; ++j) acc[i][j] = f32x4{0.f, 0.f, 0.f, 0.f};

    gemm_core_f16(Xh, Wqh, bm, bn, tid, As, Bs, acc);

    const int lane = tid & 63;
    const int l15 = lane & 15, l4 = lane >> 4;
    const int w = tid >> 6;
    const int wm = (w >> 1) * 64, wn = (w & 1) * 64;

#pragma unroll
    for (int fn = 0; fn < 4; ++fn) {
        const int c = bn * 128 + wn + fn * 16 + l15;
        const float bv = bias[c];
        const int t = c >> 10;          // 0:q 1:k 2:v (uniform per block)
        const int h = (c >> 6) & 15;
        const int d = c & 63;
        if (t < 2) {
            _Float16* dst = (t == 0) ? qf : kf;
#pragma unroll
            for (int fm = 0; fm < 4; ++fm) {
                const int rowb = bm * 128 + wm + fm * 16 + l4 * 4;
#pragma unroll
                for (int r = 0; r < 4; ++r) {
                    const int row = rowb + r;
                    const int b = row >> 11;
                    const int s = row & (S_ - 1);
                    dst[((size_t)(b * H_ + h) * S_ + s) * D_ + d] =
                        (_Float16)(acc[fm][fn][r] + bv);
                }
            }
        } else {
#pragma unroll
            for (int fm = 0; fm < 4; ++fm) {
                const int rowb = bm * 128 + wm + fm * 16 + l4 * 4;
                const int b = rowb >> 11;
                const int s0 = rowb & (S_ - 1);
                half4v pk;
#pragma unroll
                for (int r = 0; r < 4; ++r) pk[r] = (_Float16)(acc[fm][fn][r] + bv);
                *(half4v*)&vf[((size_t)(b * H_ + h) * D_ + d) * S_ + s0] = pk;
            }
        }
    }
}

// ---------------------------------------------------------------------------
// Flash attention tile compute (one 64-row q-group vs one staged 64-kpos tile).
// Swapped QK^T + pi-permuted PV (validated); + defer-max (T13) + setprio (T5).
// ---------------------------------------------------------------------------
__device__ __forceinline__ void attn_tile(
    const _Float16* __restrict__ Kb, const _Float16* __restrict__ Vb,
    const half8v (&qh)[2], f32x4 (&acc)[4],
    float& m, float& lsum,
    int k0, int qrow, int l15, int g, int swl)
{
    f32x4 qk[4];
#pragma unroll
    for (int f = 0; f < 4; ++f) qk[f] = f32x4{0.f, 0.f, 0.f, 0.f};
    __builtin_amdgcn_s_setprio(1);
#pragma unroll
    for (int s = 0; s < 2; ++s) {
#pragma unroll
        for (int f = 0; f < 4; ++f) {
            const int off = (16 * f + l15) * 64 + ((4 * s + g) ^ swl) * 8;
            half8v kv = *(const half8v*)&Kb[off];
            qk[f] = __builtin_amdgcn_mfma_f32_16x16x32_f16(kv, qh[s], qk[f], 0, 0, 0);
        }
    }
    __builtin_amdgcn_s_setprio(0);

    float p[4][4];
    float tmax = -1e30f;
#pragma unroll
    for (int f = 0; f < 4; ++f)
#pragma unroll
        for (int r = 0; r < 4; ++r) {
            const int kpos = k0 + 16 * f + 4 * g + r;
            float sv = qk[f][r] * 0.125f;
            sv = (kpos <= qrow) ? sv : -1e30f;
            p[f][r] = sv;
            tmax = fmaxf(tmax, sv);
        }
    tmax = fmaxf(tmax, __shfl_xor(tmax, 16));
    tmax = fmaxf(tmax, __shfl_xor(tmax, 32));

    // defer-max: only rescale when some row's max grew past m + 8
    if (__ballot(tmax <= m + 8.f) != ~0ull) {
        const float mnew = fmaxf(m, tmax);
        const float corr = __expf(m - mnew);
#pragma unroll
        for (int fd = 0; fd < 4; ++fd) acc[fd] *= corr;
        lsum *= corr;
        m = mnew;
    }
    float ls = 0.f;
#pragma unroll
    for (int f = 0; f < 4; ++f)
#pragma unroll
        for (int r = 0; r < 4; ++r) {
            const float e = __expf(p[f][r] - m);
            p[f][r] = e;
            ls += e;
        }
    ls += __shfl_xor(ls, 16);
    ls += __shfl_xor(ls, 32);
    lsum += ls;

    half8v pb0, pb1;
#pragma unroll
    for (int jj = 0; jj < 4; ++jj) {
        pb0[jj]     = (_Float16)p[0][jj];
        pb0[4 + jj] = (_Float16)p[1][jj];
        pb1[jj]     = (_Float16)p[2][jj];
        pb1[4 + jj] = (_Float16)p[3][jj];
    }

    __builtin_amdgcn_s_setprio(1);
#pragma unroll
    for (int t = 0; t < 2; ++t) {
        const half8v pb = t ? pb1 : pb0;
#pragma unroll
        for (int fd = 0; fd < 4; ++fd) {
            const int off = (16 * fd + l15) * 64 + ((4 * t + g) ^ swl) * 8;
            half8v vv = *(const half8v*)&Vb[off];
            acc[fd] = __builtin_amdgcn_mfma_f32_16x16x32_f16(vv, pb, acc[fd], 0, 0, 0);
        }
    }
    __builtin_amdgcn_s_setprio(0);
}

// ---------------------------------------------------------------------------
// Paired-tile fp16 flash attention (causal). Block = q-tiles {j, 31-j}
// (uniform 33 tile-units/block). Both groups share staged K/V for kb<=j.
// LDS double-buffered, ONE barrier per tile; loads issued before compute.
// ---------------------------------------------------------------------------
__global__ __launch_bounds__(256, 4)
void flash_f16_kernel(const _Float16* __restrict__ qf, const _Float16* __restrict__ kf,
                      const _Float16* __restrict__ vf, _Float16* __restrict__ ansh)
{
    const int bh = blockIdx.y;
    const int b = bh >> 4, h = bh & 15;
    const int j  = blockIdx.x;          // light q-tile
    const int jb = 31 - j;              // heavy q-tile (pair)
    const int tid = threadIdx.x;
    const int lane = tid & 63;
    const int l15 = lane & 15, g = lane >> 4;
    const int w = tid >> 6;
    const int qrowA = j * 64 + w * 16 + l15;
    const int qrowB = jb * 64 + w * 16 + l15;
    const int swl = l15 & 7;

    __shared__ _Float16 Kh[2][64 * 64];
    __shared__ _Float16 Vth[2][64 * 64];

    half8v qhA[2], qhB[2];
    {
        const _Float16* qpA = qf + ((size_t)bh * S_ + qrowA) * D_;
        const _Float16* qpB = qf + ((size_t)bh * S_ + qrowB) * D_;
#pragma unroll
        for (int s = 0; s < 2; ++s) {
            qhA[s] = *(const half8v*)(qpA + 32 * s + 8 * g);
            qhB[s] = *(const half8v*)(qpB + 32 * s + 8 * g);
        }
    }

    f32x4 accA[4], accB[4];
#pragma unroll
    for (int fd = 0; fd < 4; ++fd) {
        accA[fd] = f32x4{0.f, 0.f, 0.f, 0.f};
        accB[fd] = f32x4{0.f, 0.f, 0.f, 0.f};
    }
    float mA = -1e30f, lAs = 0.f, mB = -1e30f, lBs = 0.f;

    // staging roles (validated layout)
    const int kp = tid & 63;       // K: kpos row
    const int kw = tid >> 6;       // K: d-chunk pair
    const int vd = tid >> 2;       // V: d row
    const int vc = tid & 3;        // V: slot-chunk group
    const int vbase = 32 * (vc >> 1) + 8 * (vc & 1);

    const _Float16* Kg = kf + (size_t)bh * S_ * D_;
    const _Float16* Vg = vf + ((size_t)bh * D_ + vd) * S_;

    const int nkv = jb + 1;

    // prologue: stage tile 0 into buf 0
    {
        half8v kx0 = *(const half8v*)(Kg + (size_t)kp * D_ + 16 * kw);
        half8v kx1 = *(const half8v*)(Kg + (size_t)kp * D_ + 16 * kw + 8);
        half8v vx0 = *(const half8v*)(Vg + vbase);
        half8v vx1 = *(const half8v*)(Vg + vbase + 16);
        const int o0 = kp * 64 + ((2 * kw) ^ (kp & 7)) * 8;
        const int o1 = kp * 64 + ((2 * kw + 1) ^ (kp & 7)) * 8;
        *(half8v*)&Kh[0][o0] = kx0;
        *(half8v*)&Kh[0][o1] = kx1;
        half8v c0, c1;
#pragma unroll
        for (int jj = 0; jj < 4; ++jj) {
            c0[jj] = vx0[jj];     c0[4 + jj] = vx1[jj];
            c1[jj] = vx0[4 + jj]; c1[4 + jj] = vx1[4 + jj];
        }
        const int p0 = vd * 64 + ((2 * vc) ^ (vd & 7)) * 8;
        const int p1 = vd * 64 + ((2 * vc + 1) ^ (vd & 7)) * 8;
        *(half8v*)&Vth[0][p0] = c0;
        *(half8v*)&Vth[0][p1] = c1;
    }
    __syncthreads();

    for (int kb = 0; kb < nkv; ++kb) {
        const int cur = kb & 1;
        const int k0 = kb * 64;

        // issue next tile's global loads (hidden under compute below)
        half8v kx0, kx1, vx0, vx1;
        const bool more = (kb + 1 < nkv);
        if (more) {
            const int kn = k0 + 64;
            kx0 = *(const half8v*)(Kg + (size_t)(kn + kp) * D_ + 16 * kw);
            kx1 = *(const half8v*)(Kg + (size_t)(kn + kp) * D_ + 16 * kw + 8);
            vx0 = *(const half8v*)(Vg + kn + vbase);
            vx1 = *(const half8v*)(Vg + kn + vbase + 16);
        }

        // group B (heavy) always active; group A while kb <= j
        attn_tile(Kh[cur], Vth[cur], qhB, accB, mB, lBs, k0, qrowB, l15, g, swl);
        if (kb <= j)
            attn_tile(Kh[cur], Vth[cur], qhA, accA, mA, lAs, k0, qrowA, l15, g, swl);

        if (more) {
            const int nb = cur ^ 1;
            const int o0 = kp * 64 + ((2 * kw) ^ (kp & 7)) * 8;
            const int o1 = kp * 64 + ((2 * kw + 1) ^ (kp & 7)) * 8;
            *(half8v*)&Kh[nb][o0] = kx0;
            *(half8v*)&Kh[nb][o1] = kx1;
            half8v c0, c1;
#pragma unroll
            for (int jj = 0; jj < 4; ++jj) {
                c0[jj] = vx0[jj];     c0[4 + jj] = vx1[jj];
                c1[jj] = vx0[4 + jj]; c1[4 + jj] = vx1[4 + jj];
            }
            const int p0 = vd * 64 + ((2 * vc) ^ (vd & 7)) * 8;
            const int p1 = vd * 64 + ((2 * vc + 1) ^ (vd & 7)) * 8;
            *(half8v*)&Vth[nb][p0] = c0;
            *(half8v*)&Vth[nb][p1] = c1;
        }
        __syncthreads();
    }

    // epilogue: write both groups, ans fp16 [b,s,h,d]
    {
        const float inv = 1.f / lAs;
        _Float16* dst = ansh + ((size_t)(b * S_ + qrowA) * H_ + h) * D_;
#pragma unroll
        for (int fd = 0; fd < 4; ++fd) {
            half4v o4;
#pragma unroll
            for (int r = 0; r < 4; ++r) o4[r] = (_Float16)(accA[fd][r] * inv);
            *(half4v*)&dst[16 * fd + 4 * g] = o4;
        }
    }
    {
        const float inv = 1.f / lBs;
        _Float16* dst = ansh + ((size_t)(b * S_ + qrowB) * H_ + h) * D_;
#pragma unroll
        for (int fd = 0; fd < 4; ++fd) {
            half4v o4;
#pragma unroll
            for (int r = 0; r < 4; ++r) o4[r] = (_Float16)(accB[fd][r] * inv);
            *(half4v*)&dst[16 * fd + 4 * g] = o4;
        }
    }
}

// ---------------------------------------------------------------------------
// GEMM 2: out = ans @ W_out + b_out. A = ans fp16, Bt = W_out^T fp16.
// ---------------------------------------------------------------------------
__global__ __launch_bounds__(256, 2)
void gemm_out_f16_kernel(const _Float16* __restrict__ Ah, const _Float16* __restrict__ Woh,
                         const float* __restrict__ bias, float* __restrict__ out)
{
    __shared__ _Float16 As[128 * 64], Bs[128 * 64];
    const int tid = threadIdx.x;
    const int bm = blockIdx.x, bn = blockIdx.y;

    f32x4 acc[4][4];
#pragma unroll
    for (int i = 0; i < 4; ++i)
#pragma unroll
        for (int j = 0; j < 4; ++j) acc[i][j] = f32x4{0.f, 0.f, 0.f, 0.f};

    gemm_core_f16(Ah, Woh, bm, bn, tid, As, Bs, acc);

    const int lane = tid & 63;
    const int l15 = lane & 15, l4 = lane >> 4;
    const int w = tid >> 6;
    const int wm = (w >> 1) * 64, wn = (w & 1) * 64;

#pragma unroll
    for (int fn = 0; fn < 4; ++fn) {
        const int c = bn * 128 + wn + fn * 16 + l15;
        const float bv = bias[c];
#pragma unroll
        for (int fm = 0; fm < 4; ++fm) {
            const int rowb = bm * 128 + wm + fm * 16 + l4 * 4;
#pragma unroll
            for (int r = 0; r < 4; ++r)
                out[(size_t)(rowb + r) * E_ + c] = acc[fm][fn][r] + bv;
        }
    }
}

// ---------------------------------------------------------------------------
extern "C" void kernel_launch(void* const* d_in, const int* in_sizes, int n_in,
                              void* d_out, int out_size, void* d_ws, size_t ws_size,
                              hipStream_t stream) {
    const float* x     = (const float*)d_in[0];
    const float* W_qkv = (const float*)d_in[1];
    const float* b_qkv = (const float*)d_in[2];
    const float* W_out = (const float*)d_in[3];
    const float* b_out = (const float*)d_in[4];
    float* out = (float*)d_out;

    const size_t N1 = (size_t)B_ * H_ * S_ * D_;       // 8,388,608
    const size_t MK = (size_t)8192 * 1024;
    const size_t WQ = (size_t)3072 * 1024;
    const size_t WO = (size_t)1024 * 1024;
    const size_t need = (MK + WQ + WO + 4 * N1) * sizeof(_Float16);  // ~92 MiB
    if (ws_size < need) return;

    _Float16* Xh   = (_Float16*)d_ws;
    _Float16* Wqh  = Xh + MK;        // W_qkv^T: [3072][1024]
    _Float16* Woh  = Wqh + WQ;       // W_out^T: [1024][1024]
    _Float16* qf   = Woh + WO;       // [b,h,s,d]
    _Float16* kf   = qf + N1;        // [b,h,s,d]
    _Float16* vf   = kf + N1;        // [b,h,d,s]
    _Float16* ansh = vf + N1;        // [b,s,h,d]

    convert_f32_f16_kernel<<<(int)(MK / 4 / 256), 256, 0, stream>>>(x, Xh, (int)(MK / 4));
    transpose_f32_f16_kernel<<<dim3(16, 48), 256, 0, stream>>>(W_qkv, Wqh, 1024, 3072);
    transpose_f32_f16_kernel<<<dim3(16, 16), 256, 0, stream>>>(W_out, Woh, 1024, 1024);

    gemm_qkv_f16_kernel<<<dim3(64, 24), 256, 0, stream>>>(Xh, Wqh, b_qkv, qf, kf, vf);
    flash_f16_kernel<<<dim3(16, B_ * H_), 256, 0, stream>>>(qf, kf, vf, ansh);
    gemm_out_f16_kernel<<<dim3(64, 8), 256, 0, stream>>>(ansh, Woh, b_out, out);
}